// Round 1
// baseline (14919.987 us; speedup 1.0000x reference)
//
#include <hip/hip_runtime.h>
#include <cstdint>
#include <cstddef>

#define N_NODES  50000
#define N_GRAPHS 32
#define NODE_F   16
#define GLOBAL_F 2
#define HID      300
#define LAT      100
#define N_EDGES  800000
#define TE       32
#define KT       12

__device__ __forceinline__ float relu_f(float x){ return fmaxf(x, 0.f); }

__global__ void zero_kernel(float* __restrict__ p, int n){
  int i = blockIdx.x*blockDim.x + threadIdx.x;
  if (i < n) p[i] = 0.f;
}

__global__ void count_kernel(const int* __restrict__ ei, float* __restrict__ cnt){
  int e = blockIdx.x*blockDim.x + threadIdx.x;
  if (e < N_EDGES) atomicAdd(&cnt[ei[N_EDGES + e]], 1.f);
}

// U = x @ (W_top - W_bot), V = x @ W_bot   (factorized first edge-MLP layer)
template<int F>
__global__ __launch_bounds__(256) void node_pre_kernel(
    const float* __restrict__ xin, const float* __restrict__ w1,
    float* __restrict__ U, float* __restrict__ V){
  __shared__ float xs[8][F];
  const int n0 = blockIdx.x*8;
  const int tid = threadIdx.x;
  for (int t = tid; t < 8*F; t += 256){
    int n = t / F, k = t - n*F;
    xs[n][k] = xin[(size_t)(n0+n)*F + k];
  }
  __syncthreads();
  for (int j = tid; j < HID; j += 256){
    float uacc[8], vacc[8];
    #pragma unroll
    for (int n=0;n<8;n++){ uacc[n]=0.f; vacc[n]=0.f; }
    for (int k = 0; k < F; k += 4){
      float wtb[4], wb[4];
      #pragma unroll
      for (int t=0;t<4;t++){
        float wt = w1[(size_t)(k+t)*HID + j];
        wb[t]  = w1[(size_t)(F+k+t)*HID + j];
        wtb[t] = wt - wb[t];
      }
      #pragma unroll
      for (int n=0;n<8;n++){
        float4 xv = *(const float4*)&xs[n][k];
        uacc[n] += xv.x*wtb[0] + xv.y*wtb[1] + xv.z*wtb[2] + xv.w*wtb[3];
        vacc[n] += xv.x*wb[0]  + xv.y*wb[1]  + xv.z*wb[2]  + xv.w*wb[3];
      }
    }
    #pragma unroll
    for (int n=0;n<8;n++){
      U[(size_t)(n0+n)*HID + j] = uacc[n];
      V[(size_t)(n0+n)*HID + j] = vacc[n];
    }
  }
}

// Per-edge: h1 = relu(U[dst]+V[src]+b1); h2 = relu(h1@w2+b2); m = h2@w3;
// atomically scatter-add m into nodeacc[dst]. (b3 applied at finalize.)
__global__ __launch_bounds__(300) void edge_kernel(
    const int* __restrict__ ei,
    const float* __restrict__ U, const float* __restrict__ V,
    const float* __restrict__ b1, const float* __restrict__ w2,
    const float* __restrict__ b2, const float* __restrict__ w3,
    float* __restrict__ nodeacc){
  __shared__ float hbuf[TE][HID];   // h1, then overwritten with h2
  __shared__ float wpan[KT][HID];   // staged weight K-panel
  __shared__ int sdst[TE], ssrc[TE];
  const int tid = threadIdx.x;
  const int e0 = blockIdx.x * TE;
  if (tid < TE){ ssrc[tid] = ei[e0 + tid]; sdst[tid] = ei[N_EDGES + e0 + tid]; }
  __syncthreads();
  // gather h1
  for (int t = tid; t < TE*(HID/4); t += 300){
    int e  = t / (HID/4);
    int k4 = (t - e*(HID/4))*4;
    const float4 uu = *(const float4*)&U[(size_t)sdst[e]*HID + k4];
    const float4 vv = *(const float4*)&V[(size_t)ssrc[e]*HID + k4];
    const float4 bb = *(const float4*)&b1[k4];
    float4 h;
    h.x = relu_f(uu.x+vv.x+bb.x); h.y = relu_f(uu.y+vv.y+bb.y);
    h.z = relu_f(uu.z+vv.z+bb.z); h.w = relu_f(uu.w+vv.w+bb.w);
    *(float4*)&hbuf[e][k4] = h;
  }
  // ---- GEMM1: [TE][300] = h1 @ w2[300][300] ----
  const int tx = tid % 75;   // cols 4tx..4tx+3
  const int ty = tid / 75;   // 0..3 -> edges ty*8..+7
  float c1[8][4];
  #pragma unroll
  for (int i=0;i<8;i++){
    #pragma unroll
    for (int jj=0;jj<4;jj++) c1[i][jj]=0.f;
  }
  for (int kp = 0; kp < HID; kp += KT){
    __syncthreads();
    #pragma unroll
    for (int t0 = 0; t0 < 3; t0++){
      int t = tid + t0*300;
      int r = t / 75, cc = (t - r*75)*4;
      *(float4*)&wpan[r][cc] = *(const float4*)&w2[(size_t)(kp+r)*HID + cc];
    }
    __syncthreads();
    #pragma unroll
    for (int kk = 0; kk < KT; kk += 4){
      float4 bfr[4];
      #pragma unroll
      for (int t=0;t<4;t++) bfr[t] = *(const float4*)&wpan[kk+t][tx*4];
      #pragma unroll
      for (int i=0;i<8;i++){
        float4 a = *(const float4*)&hbuf[ty*8+i][kp+kk];
        c1[i][0] += a.x*bfr[0].x + a.y*bfr[1].x + a.z*bfr[2].x + a.w*bfr[3].x;
        c1[i][1] += a.x*bfr[0].y + a.y*bfr[1].y + a.z*bfr[2].y + a.w*bfr[3].y;
        c1[i][2] += a.x*bfr[0].z + a.y*bfr[1].z + a.z*bfr[2].z + a.w*bfr[3].z;
        c1[i][3] += a.x*bfr[0].w + a.y*bfr[1].w + a.z*bfr[2].w + a.w*bfr[3].w;
      }
    }
  }
  __syncthreads();  // all h1 reads done; safe to overwrite hbuf with h2
  {
    const float4 b2v = *(const float4*)&b2[tx*4];
    #pragma unroll
    for (int i=0;i<8;i++){
      float4 h2v;
      h2v.x = relu_f(c1[i][0]+b2v.x); h2v.y = relu_f(c1[i][1]+b2v.y);
      h2v.z = relu_f(c1[i][2]+b2v.z); h2v.w = relu_f(c1[i][3]+b2v.w);
      *(float4*)&hbuf[ty*8+i][tx*4] = h2v;
    }
  }
  // ---- GEMM2: [TE][100] = h2 @ w3[300][100] ----
  const int tx2 = tid % 25;  // cols 4tx2..4tx2+3
  const int ty2 = tid / 25;  // 0..11 -> edges ty2*3..+2 (guard e<32)
  float c2[3][4];
  #pragma unroll
  for (int i=0;i<3;i++){
    #pragma unroll
    for (int jj=0;jj<4;jj++) c2[i][jj]=0.f;
  }
  for (int kp = 0; kp < HID; kp += KT){
    __syncthreads();
    {
      int r = tid / 25, cc = (tid - (tid/25)*25)*4;
      *(float4*)&wpan[r][cc] = *(const float4*)&w3[(size_t)(kp+r)*LAT + cc];
    }
    __syncthreads();
    #pragma unroll
    for (int kk=0;kk<KT;kk+=4){
      float4 bfr[4];
      #pragma unroll
      for (int t=0;t<4;t++) bfr[t] = *(const float4*)&wpan[kk+t][tx2*4];
      #pragma unroll
      for (int i=0;i<3;i++){
        int e = ty2*3+i; int ee = (e < TE) ? e : 0;
        float4 a = *(const float4*)&hbuf[ee][kp+kk];
        c2[i][0] += a.x*bfr[0].x + a.y*bfr[1].x + a.z*bfr[2].x + a.w*bfr[3].x;
        c2[i][1] += a.x*bfr[0].y + a.y*bfr[1].y + a.z*bfr[2].y + a.w*bfr[3].y;
        c2[i][2] += a.x*bfr[0].z + a.y*bfr[1].z + a.z*bfr[2].z + a.w*bfr[3].z;
        c2[i][3] += a.x*bfr[0].w + a.y*bfr[1].w + a.z*bfr[2].w + a.w*bfr[3].w;
      }
    }
  }
  #pragma unroll
  for (int i=0;i<3;i++){
    int e = ty2*3+i;
    if (e < TE){
      const size_t base = (size_t)sdst[e]*LAT + tx2*4;
      atomicAdd(&nodeacc[base+0], c2[i][0]);
      atomicAdd(&nodeacc[base+1], c2[i][1]);
      atomicAdd(&nodeacc[base+2], c2[i][2]);
      atomicAdd(&nodeacc[base+3], c2[i][3]);
    }
  }
}

// x_out = relu(acc/max(cnt,1) + (cnt>0 ? b3 : 0)); also re-zero acc for next layer
__global__ void finalize_kernel(float* __restrict__ nodeacc, const float* __restrict__ cnt,
                                const float* __restrict__ b3, float* __restrict__ xout){
  int idx = blockIdx.x*blockDim.x + threadIdx.x;
  if (idx < N_NODES*LAT){
    int n = idx / LAT, j = idx - n*LAT;
    float c = cnt[n];
    float v = nodeacc[idx] / fmaxf(c, 1.f);
    v += (c > 0.f) ? b3[j] : 0.f;
    xout[idx] = relu_f(v);
    nodeacc[idx] = 0.f;
  }
}

__global__ void pool_kernel(const float* __restrict__ x2, const int* __restrict__ batch,
                            float* __restrict__ gacc, float* __restrict__ gcnt){
  int idx = blockIdx.x*blockDim.x + threadIdx.x;
  if (idx < N_NODES*LAT){
    int n = idx / LAT, j = idx - n*LAT;
    int g = batch[n];
    atomicAdd(&gacc[g*LAT + j], x2[idx]);
    if (j == 0) atomicAdd(&gcnt[g], 1.f);
  }
}

__global__ __launch_bounds__(128) void head_kernel(
    const float* __restrict__ gacc, const float* __restrict__ gcnt,
    const float* __restrict__ u,
    const float* __restrict__ w1, const float* __restrict__ bb1,
    const float* __restrict__ w2, const float* __restrict__ bb2,
    const float* __restrict__ w3, const float* __restrict__ bb3,
    float* __restrict__ out){
  __shared__ float p[N_GRAPHS][LAT+GLOBAL_F];
  __shared__ float h1[N_GRAPHS][LAT];
  __shared__ float h2[N_GRAPHS][LAT];
  const int tid = threadIdx.x;
  for (int t = tid; t < N_GRAPHS*LAT; t += 128){
    int g = t / LAT, k = t - g*LAT;
    p[g][k] = gacc[t] / fmaxf(gcnt[g], 1.f);
  }
  for (int t = tid; t < N_GRAPHS*GLOBAL_F; t += 128){
    int g = t / GLOBAL_F, c = t - g*GLOBAL_F;
    p[g][LAT + c] = u[t];
  }
  __syncthreads();
  for (int t = tid; t < N_GRAPHS*LAT; t += 128){
    int g = t / LAT, j = t - g*LAT;
    float s = bb1[j];
    for (int k = 0; k < LAT+GLOBAL_F; k++) s += p[g][k]*w1[(size_t)k*LAT + j];
    h1[g][j] = relu_f(s);
  }
  __syncthreads();
  for (int t = tid; t < N_GRAPHS*LAT; t += 128){
    int g = t / LAT, j = t - g*LAT;
    float s = bb2[j];
    for (int k = 0; k < LAT; k++) s += h1[g][k]*w2[(size_t)k*LAT + j];
    h2[g][j] = relu_f(s);
  }
  __syncthreads();
  for (int t = tid; t < N_GRAPHS; t += 128){
    float s = bb3[0];
    for (int k = 0; k < LAT; k++) s += h2[t][k]*w3[k];
    out[t] = s;
  }
}

extern "C" void kernel_launch(void* const* d_in, const int* in_sizes, int n_in,
                              void* d_out, int out_size, void* d_ws, size_t ws_size,
                              hipStream_t stream){
  (void)in_sizes; (void)n_in; (void)out_size; (void)ws_size;
  const float* x     = (const float*)d_in[0];
  const int*   ei    = (const int*)d_in[1];
  const int*   batch = (const int*)d_in[2];
  const float* u     = (const float*)d_in[3];
  const float* l0_w1 = (const float*)d_in[4];  const float* l0_b1 = (const float*)d_in[5];
  const float* l0_w2 = (const float*)d_in[6];  const float* l0_b2 = (const float*)d_in[7];
  const float* l0_w3 = (const float*)d_in[8];  const float* l0_b3 = (const float*)d_in[9];
  const float* l1_w1 = (const float*)d_in[10]; const float* l1_b1 = (const float*)d_in[11];
  const float* l1_w2 = (const float*)d_in[12]; const float* l1_b2 = (const float*)d_in[13];
  const float* l1_w3 = (const float*)d_in[14]; const float* l1_b3 = (const float*)d_in[15];
  const float* lin_w1= (const float*)d_in[16]; const float* lin_b1= (const float*)d_in[17];
  const float* lin_w2= (const float*)d_in[18]; const float* lin_b2= (const float*)d_in[19];
  const float* lin_w3= (const float*)d_in[20]; const float* lin_b3= (const float*)d_in[21];

  float* ws      = (float*)d_ws;
  float* U       = ws;                                   // [N,300]
  float* V       = U + (size_t)N_NODES*HID;              // [N,300]
  float* nodeacc = V + (size_t)N_NODES*HID;              // [N,100]
  float* cnt     = nodeacc + (size_t)N_NODES*LAT;        // [N]
  float* gacc    = cnt + N_NODES;                        // [32,100]
  float* gcnt    = gacc + N_GRAPHS*LAT;                  // [32]
  float* x1      = gcnt + N_GRAPHS;                      // [N,100] (layer0 out, then layer1 out)

  // zero nodeacc + cnt + gacc + gcnt (contiguous)
  {
    int zn = N_NODES*LAT + N_NODES + N_GRAPHS*LAT + N_GRAPHS;
    hipLaunchKernelGGL(zero_kernel, dim3((zn+255)/256), dim3(256), 0, stream, nodeacc, zn);
  }
  hipLaunchKernelGGL(count_kernel, dim3((N_EDGES+255)/256), dim3(256), 0, stream, ei, cnt);

  // layer 0
  hipLaunchKernelGGL(node_pre_kernel<NODE_F>, dim3(N_NODES/8), dim3(256), 0, stream, x, l0_w1, U, V);
  hipLaunchKernelGGL(edge_kernel, dim3(N_EDGES/TE), dim3(300), 0, stream,
                     ei, U, V, l0_b1, l0_w2, l0_b2, l0_w3, nodeacc);
  hipLaunchKernelGGL(finalize_kernel, dim3((N_NODES*LAT+255)/256), dim3(256), 0, stream,
                     nodeacc, cnt, l0_b3, x1);

  // layer 1
  hipLaunchKernelGGL(node_pre_kernel<LAT>, dim3(N_NODES/8), dim3(256), 0, stream, x1, l1_w1, U, V);
  hipLaunchKernelGGL(edge_kernel, dim3(N_EDGES/TE), dim3(300), 0, stream,
                     ei, U, V, l1_b1, l1_w2, l1_b2, l1_w3, nodeacc);
  hipLaunchKernelGGL(finalize_kernel, dim3((N_NODES*LAT+255)/256), dim3(256), 0, stream,
                     nodeacc, cnt, l1_b3, x1);

  // pooling + head
  hipLaunchKernelGGL(pool_kernel, dim3((N_NODES*LAT+255)/256), dim3(256), 0, stream,
                     x1, batch, gacc, gcnt);
  hipLaunchKernelGGL(head_kernel, dim3(1), dim3(128), 0, stream,
                     gacc, gcnt, u, lin_w1, lin_b1, lin_w2, lin_b2, lin_w3, lin_b3,
                     (float*)d_out);
}

// Round 2
// 2247.504 us; speedup vs baseline: 6.6385x; 6.6385x over previous
//
#include <hip/hip_runtime.h>
#include <cstdint>
#include <cstddef>

#define N_NODES  50000
#define N_GRAPHS 32
#define NODE_F   16
#define GLOBAL_F 2
#define HID      300
#define LAT      100
#define N_EDGES  800000

#define HIDP 320            // padded K / hidden (multiple of 32)
#define LATP 128            // padded GEMM2 output cols (multiple of 16)
#define NCT1 (HIDP/16)      // 20 col-tiles GEMM1
#define NCT2 (LATP/16)      // 8  col-tiles GEMM2
#define NKS  (HIDP/32)      // 10 k-steps
#define EPB  64             // edges per block
#define ROWP 66             // padded row count in chunked LDS layout (bank skew)

typedef __bf16 bf16x8 __attribute__((ext_vector_type(8)));
typedef float  f32x4  __attribute__((ext_vector_type(4)));

__device__ __forceinline__ float relu_f(float x){ return fmaxf(x, 0.f); }

__device__ __forceinline__ unsigned short f2bf(float x){
  unsigned int u = __float_as_uint(x);
  u = (u + 0x7FFFu + ((u >> 16) & 1u)) >> 16;   // RNE
  return (unsigned short)u;
}
__device__ __forceinline__ float bf2f(unsigned int h){
  return __uint_as_float(h << 16);
}

__global__ void zero_kernel(float* __restrict__ p, int n){
  int i = blockIdx.x*blockDim.x + threadIdx.x;
  if (i < n) p[i] = 0.f;
}

__global__ void count_kernel(const int* __restrict__ ei, float* __restrict__ cnt){
  int e = blockIdx.x*blockDim.x + threadIdx.x;
  if (e < N_EDGES) atomicAdd(&cnt[ei[N_EDGES + e]], 1.f);
}

// Pack weight [K][N] fp32 -> fragment-ordered bf16: out[ks][ct][lane][8]
// B-frag for 16x16x32: lane l holds B[k=32ks+8*(l>>4)+j][n=16ct+(l&15)], j=0..7
__global__ void pack_wfrag(const float* __restrict__ w, int K, int N, int nct,
                           unsigned short* __restrict__ out, int total){
  int i = blockIdx.x*blockDim.x + threadIdx.x;
  if (i >= total) return;
  int j  = i & 7;
  int l  = (i >> 3) & 63;
  int t  = i >> 9;
  int ct = t % nct, ks = t / nct;
  int n = ct*16 + (l & 15);
  int k = ks*32 + ((l >> 4) << 3) + j;
  float v = (k < K && n < N) ? w[(size_t)k*N + n] : 0.f;
  out[i] = f2bf(v);
}

__global__ void pad_bias(const float* __restrict__ b, int K, float* __restrict__ out){
  int i = blockIdx.x*blockDim.x + threadIdx.x;
  if (i < HIDP) out[i] = (i < K) ? b[i] : 0.f;
}

// U = x @ (W_top - W_bot), V = x @ W_bot  -> bf16, padded to HIDP cols (pads = 0)
template<int F>
__global__ __launch_bounds__(256) void node_pre_bf16(
    const float* __restrict__ xin, const float* __restrict__ w1,
    unsigned short* __restrict__ U, unsigned short* __restrict__ V){
  __shared__ float xs[8][F];
  const int n0 = blockIdx.x*8;
  const int tid = threadIdx.x;
  for (int t = tid; t < 8*F; t += 256){
    int n = t / F, k = t - n*F;
    xs[n][k] = xin[(size_t)(n0+n)*F + k];
  }
  __syncthreads();
  if (tid < 160){
    const int j0 = tid*2;
    if (j0 < HID){
      float ua[8][2], va[8][2];
      #pragma unroll
      for (int n=0;n<8;n++){ ua[n][0]=0.f; ua[n][1]=0.f; va[n][0]=0.f; va[n][1]=0.f; }
      for (int k = 0; k < F; ++k){
        const float2 wt = *(const float2*)&w1[(size_t)k*HID + j0];
        const float2 wb = *(const float2*)&w1[(size_t)(F+k)*HID + j0];
        const float wtb0 = wt.x - wb.x, wtb1 = wt.y - wb.y;
        #pragma unroll
        for (int n=0;n<8;n++){
          float xv = xs[n][k];
          ua[n][0] += xv*wtb0; ua[n][1] += xv*wtb1;
          va[n][0] += xv*wb.x; va[n][1] += xv*wb.y;
        }
      }
      #pragma unroll
      for (int n=0;n<8;n++){
        unsigned int pu = (unsigned int)f2bf(ua[n][0]) | ((unsigned int)f2bf(ua[n][1]) << 16);
        unsigned int pv = (unsigned int)f2bf(va[n][0]) | ((unsigned int)f2bf(va[n][1]) << 16);
        *(unsigned int*)&U[(size_t)(n0+n)*HIDP + j0] = pu;
        *(unsigned int*)&V[(size_t)(n0+n)*HIDP + j0] = pv;
      }
    } else {
      #pragma unroll
      for (int n=0;n<8;n++){
        *(unsigned int*)&U[(size_t)(n0+n)*HIDP + j0] = 0u;
        *(unsigned int*)&V[(size_t)(n0+n)*HIDP + j0] = 0u;
      }
    }
  }
}

// Per 64-edge tile: gather h1 = relu(U[dst]+V[src]+b1) -> LDS (bf16, chunked A-frag
// layout hs[k/8][row][8]); GEMM1 (MFMA) -> h2 -> LDS; GEMM2 (MFMA) -> atomic scatter.
__global__ __launch_bounds__(256, 3) void edge_mfma(
    const int* __restrict__ ei,
    const unsigned short* __restrict__ U, const unsigned short* __restrict__ V,
    const float* __restrict__ b1p, const unsigned short* __restrict__ w2f,
    const float* __restrict__ b2p, const unsigned short* __restrict__ w3f,
    float* __restrict__ nodeacc){
  __shared__ __align__(16) unsigned short hs[HIDP/8][ROWP][8];
  __shared__ int sdst[EPB], ssrc[EPB];
  const int tid = threadIdx.x;
  const int e0 = blockIdx.x * EPB;
  if (tid < EPB){ ssrc[tid] = ei[e0 + tid]; sdst[tid] = ei[N_EDGES + e0 + tid]; }
  __syncthreads();

  // ---- gather + h1 ----
  #pragma unroll
  for (int it = 0; it < 10; ++it){
    int i = tid + it*256;          // 2560 = 40 chunks x 64 edges
    int c = i >> 6, e = i & 63;
    const uint4 uu = *(const uint4*)&U[(size_t)sdst[e]*HIDP + c*8];
    const uint4 vv = *(const uint4*)&V[(size_t)ssrc[e]*HIDP + c*8];
    const float4 bl = *(const float4*)&b1p[c*8];
    const float4 bh = *(const float4*)&b1p[c*8 + 4];
    const unsigned int uarr[4] = {uu.x, uu.y, uu.z, uu.w};
    const unsigned int varr[4] = {vv.x, vv.y, vv.z, vv.w};
    const float barr[8] = {bl.x, bl.y, bl.z, bl.w, bh.x, bh.y, bh.z, bh.w};
    unsigned int ou[4];
    #pragma unroll
    for (int q = 0; q < 4; ++q){
      float f0 = bf2f(uarr[q] & 0xFFFFu) + bf2f(varr[q] & 0xFFFFu) + barr[2*q];
      float f1 = bf2f(uarr[q] >> 16)     + bf2f(varr[q] >> 16)     + barr[2*q+1];
      f0 = relu_f(f0); f1 = relu_f(f1);
      ou[q] = (unsigned int)f2bf(f0) | ((unsigned int)f2bf(f1) << 16);
    }
    *(uint4*)&hs[c][e][0] = make_uint4(ou[0], ou[1], ou[2], ou[3]);
  }
  __syncthreads();

  const int wave = tid >> 6, l = tid & 63;
  const int lrow = l & 15, lq = l >> 4;

  // ---- GEMM1: [64 x 320] = h1 @ w2 ----
  f32x4 acc1[4][5];
  #pragma unroll
  for (int rt = 0; rt < 4; ++rt)
    #pragma unroll
    for (int c = 0; c < 5; ++c)
      acc1[rt][c] = (f32x4){0.f, 0.f, 0.f, 0.f};

  for (int ks = 0; ks < NKS; ++ks){
    bf16x8 a[4];
    #pragma unroll
    for (int rt = 0; rt < 4; ++rt)
      a[rt] = __builtin_bit_cast(bf16x8, *(const uint4*)&hs[4*ks + lq][16*rt + lrow][0]);
    #pragma unroll
    for (int c = 0; c < 5; ++c){
      int ct = wave*5 + c;
      bf16x8 b = __builtin_bit_cast(bf16x8,
                   *(const uint4*)&w2f[(((size_t)(ks*NCT1 + ct)) << 9) + l*8]);
      #pragma unroll
      for (int rt = 0; rt < 4; ++rt)
        acc1[rt][c] = __builtin_amdgcn_mfma_f32_16x16x32_bf16(a[rt], b, acc1[rt][c], 0, 0, 0);
    }
  }
  __syncthreads();   // all h1 reads done

  // ---- epilogue1: h2 = relu(C1 + b2) -> hs (chunked layout) ----
  #pragma unroll
  for (int c = 0; c < 5; ++c){
    int col = (wave*5 + c)*16 + lrow;
    float b2v = b2p[col];
    #pragma unroll
    for (int rt = 0; rt < 4; ++rt){
      #pragma unroll
      for (int r = 0; r < 4; ++r){
        int row = rt*16 + lq*4 + r;
        hs[col >> 3][row][col & 7] = f2bf(relu_f(acc1[rt][c][r] + b2v));
      }
    }
  }
  __syncthreads();

  // ---- GEMM2: [64 x 128] = h2 @ w3 ----
  f32x4 acc2[4][2];
  #pragma unroll
  for (int rt = 0; rt < 4; ++rt)
    #pragma unroll
    for (int c = 0; c < 2; ++c)
      acc2[rt][c] = (f32x4){0.f, 0.f, 0.f, 0.f};

  for (int ks = 0; ks < NKS; ++ks){
    bf16x8 a[4];
    #pragma unroll
    for (int rt = 0; rt < 4; ++rt)
      a[rt] = __builtin_bit_cast(bf16x8, *(const uint4*)&hs[4*ks + lq][16*rt + lrow][0]);
    #pragma unroll
    for (int c = 0; c < 2; ++c){
      int ct = wave*2 + c;
      bf16x8 b = __builtin_bit_cast(bf16x8,
                   *(const uint4*)&w3f[(((size_t)(ks*NCT2 + ct)) << 9) + l*8]);
      #pragma unroll
      for (int rt = 0; rt < 4; ++rt)
        acc2[rt][c] = __builtin_amdgcn_mfma_f32_16x16x32_bf16(a[rt], b, acc2[rt][c], 0, 0, 0);
    }
  }

  // ---- scatter-add (cols < 100) ----
  #pragma unroll
  for (int c = 0; c < 2; ++c){
    int col = (wave*2 + c)*16 + lrow;
    if (col < LAT){
      #pragma unroll
      for (int rt = 0; rt < 4; ++rt){
        #pragma unroll
        for (int r = 0; r < 4; ++r){
          int row = rt*16 + lq*4 + r;
          atomicAdd(&nodeacc[(size_t)sdst[row]*LAT + col], acc2[rt][c][r]);
        }
      }
    }
  }
}

// x_out = relu(acc/max(cnt,1) + (cnt>0 ? b3 : 0)); re-zero acc for next layer
__global__ void finalize_kernel(float* __restrict__ nodeacc, const float* __restrict__ cnt,
                                const float* __restrict__ b3, float* __restrict__ xout){
  int idx = blockIdx.x*blockDim.x + threadIdx.x;
  if (idx < N_NODES*LAT){
    int n = idx / LAT, j = idx - n*LAT;
    float c = cnt[n];
    float v = nodeacc[idx] / fmaxf(c, 1.f);
    v += (c > 0.f) ? b3[j] : 0.f;
    xout[idx] = relu_f(v);
    nodeacc[idx] = 0.f;
  }
}

__global__ void pool_kernel(const float* __restrict__ x2, const int* __restrict__ batch,
                            float* __restrict__ gacc, float* __restrict__ gcnt){
  int idx = blockIdx.x*blockDim.x + threadIdx.x;
  if (idx < N_NODES*LAT){
    int n = idx / LAT, j = idx - n*LAT;
    int g = batch[n];
    atomicAdd(&gacc[g*LAT + j], x2[idx]);
    if (j == 0) atomicAdd(&gcnt[g], 1.f);
  }
}

__global__ __launch_bounds__(128) void head_kernel(
    const float* __restrict__ gacc, const float* __restrict__ gcnt,
    const float* __restrict__ u,
    const float* __restrict__ w1, const float* __restrict__ bb1,
    const float* __restrict__ w2, const float* __restrict__ bb2,
    const float* __restrict__ w3, const float* __restrict__ bb3,
    float* __restrict__ out){
  __shared__ float p[N_GRAPHS][LAT+GLOBAL_F];
  __shared__ float h1[N_GRAPHS][LAT];
  __shared__ float h2[N_GRAPHS][LAT];
  const int tid = threadIdx.x;
  for (int t = tid; t < N_GRAPHS*LAT; t += 128){
    int g = t / LAT, k = t - g*LAT;
    p[g][k] = gacc[t] / fmaxf(gcnt[g], 1.f);
  }
  for (int t = tid; t < N_GRAPHS*GLOBAL_F; t += 128){
    int g = t / GLOBAL_F, c = t - g*GLOBAL_F;
    p[g][LAT + c] = u[t];
  }
  __syncthreads();
  for (int t = tid; t < N_GRAPHS*LAT; t += 128){
    int g = t / LAT, j = t - g*LAT;
    float s = bb1[j];
    for (int k = 0; k < LAT+GLOBAL_F; k++) s += p[g][k]*w1[(size_t)k*LAT + j];
    h1[g][j] = relu_f(s);
  }
  __syncthreads();
  for (int t = tid; t < N_GRAPHS*LAT; t += 128){
    int g = t / LAT, j = t - g*LAT;
    float s = bb2[j];
    for (int k = 0; k < LAT; k++) s += h1[g][k]*w2[(size_t)k*LAT + j];
    h2[g][j] = relu_f(s);
  }
  __syncthreads();
  for (int t = tid; t < N_GRAPHS; t += 128){
    float s = bb3[0];
    for (int k = 0; k < LAT; k++) s += h2[t][k]*w3[k];
    out[t] = s;
  }
}

extern "C" void kernel_launch(void* const* d_in, const int* in_sizes, int n_in,
                              void* d_out, int out_size, void* d_ws, size_t ws_size,
                              hipStream_t stream){
  (void)in_sizes; (void)n_in; (void)out_size; (void)ws_size;
  const float* x     = (const float*)d_in[0];
  const int*   ei    = (const int*)d_in[1];
  const int*   batch = (const int*)d_in[2];
  const float* u     = (const float*)d_in[3];
  const float* l0_w1 = (const float*)d_in[4];  const float* l0_b1 = (const float*)d_in[5];
  const float* l0_w2 = (const float*)d_in[6];  const float* l0_b2 = (const float*)d_in[7];
  const float* l0_w3 = (const float*)d_in[8];  const float* l0_b3 = (const float*)d_in[9];
  const float* l1_w1 = (const float*)d_in[10]; const float* l1_b1 = (const float*)d_in[11];
  const float* l1_w2 = (const float*)d_in[12]; const float* l1_b2 = (const float*)d_in[13];
  const float* l1_w3 = (const float*)d_in[14]; const float* l1_b3 = (const float*)d_in[15];
  const float* lin_w1= (const float*)d_in[16]; const float* lin_b1= (const float*)d_in[17];
  const float* lin_w2= (const float*)d_in[18]; const float* lin_b2= (const float*)d_in[19];
  const float* lin_w3= (const float*)d_in[20]; const float* lin_b3= (const float*)d_in[21];

  char* wsb = (char*)d_ws;
  const size_t UV_BYTES  = (size_t)N_NODES*HIDP*sizeof(unsigned short); // 32 MB each
  const size_t W2F_ELEMS = (size_t)NKS*NCT1*512;   // 102400
  const size_t W3F_ELEMS = (size_t)NKS*NCT2*512;   // 40960

  unsigned short* Ub   = (unsigned short*)wsb;                 wsb += UV_BYTES;
  unsigned short* Vb   = (unsigned short*)wsb;                 wsb += UV_BYTES;
  unsigned short* w2f0 = (unsigned short*)wsb;                 wsb += W2F_ELEMS*2;
  unsigned short* w3f0 = (unsigned short*)wsb;                 wsb += W3F_ELEMS*2;
  unsigned short* w2f1 = (unsigned short*)wsb;                 wsb += W2F_ELEMS*2;
  unsigned short* w3f1 = (unsigned short*)wsb;                 wsb += W3F_ELEMS*2;
  float* b1p0 = (float*)wsb;                                   wsb += HIDP*4;
  float* b2p0 = (float*)wsb;                                   wsb += HIDP*4;
  float* b1p1 = (float*)wsb;                                   wsb += HIDP*4;
  float* b2p1 = (float*)wsb;                                   wsb += HIDP*4;
  float* nodeacc = (float*)wsb;                                wsb += (size_t)N_NODES*LAT*4;
  float* cnt     = (float*)wsb;                                wsb += (size_t)N_NODES*4;
  float* gacc    = (float*)wsb;                                wsb += (size_t)N_GRAPHS*LAT*4;
  float* gcnt    = (float*)wsb;                                wsb += (size_t)N_GRAPHS*4;
  float* x1      = (float*)wsb;                                wsb += (size_t)N_NODES*LAT*4;

  // zero nodeacc + cnt + gacc + gcnt (contiguous)
  {
    int zn = N_NODES*LAT + N_NODES + N_GRAPHS*LAT + N_GRAPHS;
    hipLaunchKernelGGL(zero_kernel, dim3((zn+255)/256), dim3(256), 0, stream, nodeacc, zn);
  }
  hipLaunchKernelGGL(count_kernel, dim3((N_EDGES+255)/256), dim3(256), 0, stream, ei, cnt);

  // weight / bias prep (both layers)
  hipLaunchKernelGGL(pack_wfrag, dim3((W2F_ELEMS+255)/256), dim3(256), 0, stream,
                     l0_w2, HID, HID, NCT1, w2f0, (int)W2F_ELEMS);
  hipLaunchKernelGGL(pack_wfrag, dim3((W3F_ELEMS+255)/256), dim3(256), 0, stream,
                     l0_w3, HID, LAT, NCT2, w3f0, (int)W3F_ELEMS);
  hipLaunchKernelGGL(pack_wfrag, dim3((W2F_ELEMS+255)/256), dim3(256), 0, stream,
                     l1_w2, HID, HID, NCT1, w2f1, (int)W2F_ELEMS);
  hipLaunchKernelGGL(pack_wfrag, dim3((W3F_ELEMS+255)/256), dim3(256), 0, stream,
                     l1_w3, HID, LAT, NCT2, w3f1, (int)W3F_ELEMS);
  hipLaunchKernelGGL(pad_bias, dim3(2), dim3(256), 0, stream, l0_b1, HID, b1p0);
  hipLaunchKernelGGL(pad_bias, dim3(2), dim3(256), 0, stream, l0_b2, HID, b2p0);
  hipLaunchKernelGGL(pad_bias, dim3(2), dim3(256), 0, stream, l1_b1, HID, b1p1);
  hipLaunchKernelGGL(pad_bias, dim3(2), dim3(256), 0, stream, l1_b2, HID, b2p1);

  // layer 0
  hipLaunchKernelGGL(node_pre_bf16<NODE_F>, dim3(N_NODES/8), dim3(256), 0, stream,
                     x, l0_w1, Ub, Vb);
  hipLaunchKernelGGL(edge_mfma, dim3(N_EDGES/EPB), dim3(256), 0, stream,
                     ei, Ub, Vb, b1p0, w2f0, b2p0, w3f0, nodeacc);
  hipLaunchKernelGGL(finalize_kernel, dim3((N_NODES*LAT+255)/256), dim3(256), 0, stream,
                     nodeacc, cnt, l0_b3, x1);

  // layer 1
  hipLaunchKernelGGL(node_pre_bf16<LAT>, dim3(N_NODES/8), dim3(256), 0, stream,
                     x1, l1_w1, Ub, Vb);
  hipLaunchKernelGGL(edge_mfma, dim3(N_EDGES/EPB), dim3(256), 0, stream,
                     ei, Ub, Vb, b1p1, w2f1, b2p1, w3f1, nodeacc);
  hipLaunchKernelGGL(finalize_kernel, dim3((N_NODES*LAT+255)/256), dim3(256), 0, stream,
                     nodeacc, cnt, l1_b3, x1);

  // pooling + head
  hipLaunchKernelGGL(pool_kernel, dim3((N_NODES*LAT+255)/256), dim3(256), 0, stream,
                     x1, batch, gacc, gcnt);
  hipLaunchKernelGGL(head_kernel, dim3(1), dim3(128), 0, stream,
                     gacc, gcnt, u, lin_w1, lin_b1, lin_w2, lin_b2, lin_w3, lin_b3,
                     (float*)d_out);
}

// Round 3
// 1941.992 us; speedup vs baseline: 7.6828x; 1.1573x over previous
//
#include <hip/hip_runtime.h>
#include <cstdint>
#include <cstddef>

#define N_NODES  50000
#define N_GRAPHS 32
#define NODE_F   16
#define GLOBAL_F 2
#define HID      300
#define LAT      100
#define N_EDGES  800000

#define HIDP 320            // padded K / hidden (multiple of 32)
#define LATP 128            // padded GEMM2 output cols
#define NCT1 (HIDP/16)      // 20 col-tiles GEMM1
#define NCT2 (LATP/16)      // 8  col-tiles GEMM2
#define NKS  (HIDP/32)      // 10 k-steps
#define EPB  64             // edges per block
#define ROWP 66             // padded row count in chunked LDS layout

typedef __bf16 bf16x8 __attribute__((ext_vector_type(8)));
typedef float  f32x4  __attribute__((ext_vector_type(4)));

__device__ __forceinline__ float relu_f(float x){ return fmaxf(x, 0.f); }

__device__ __forceinline__ unsigned short f2bf(float x){   // RNE, for prep kernels
  unsigned int u = __float_as_uint(x);
  u = (u + 0x7FFFu + ((u >> 16) & 1u)) >> 16;
  return (unsigned short)u;
}
__device__ __forceinline__ unsigned short f2bf_hw(float x){ // hot path: hw convert
  __bf16 h = (__bf16)x;
  return __builtin_bit_cast(unsigned short, h);
}
__device__ __forceinline__ float bf2f(unsigned int h){
  return __uint_as_float(h << 16);
}

__global__ void zero_kernel(float* __restrict__ p, int n){
  int i = blockIdx.x*blockDim.x + threadIdx.x;
  if (i < n) p[i] = 0.f;
}

__global__ void hist_kernel(const int* __restrict__ ei, int* __restrict__ hist){
  int e = blockIdx.x*blockDim.x + threadIdx.x;
  if (e < N_EDGES) atomicAdd(&hist[ei[N_EDGES + e]], 1);
}

// single-block exclusive scan of hist -> woff (write cursor per node)
__global__ __launch_bounds__(256) void scan_kernel(const int* __restrict__ hist,
                                                   int* __restrict__ woff){
  __shared__ int part[256];
  const int t = threadIdx.x;
  const int CH = (N_NODES + 255) / 256;        // 196
  const int lo = t*CH, hi = (lo + CH < N_NODES) ? lo + CH : N_NODES;
  int s = 0;
  for (int i = lo; i < hi; ++i) s += hist[i];
  part[t] = s;
  __syncthreads();
  for (int d = 1; d < 256; d <<= 1){
    int v = (t >= d) ? part[t-d] : 0;
    __syncthreads();
    part[t] += v;
    __syncthreads();
  }
  int run = (t == 0) ? 0 : part[t-1];
  for (int i = lo; i < hi; ++i){ woff[i] = run; run += hist[i]; }
}

// counting-sort scatter: edges grouped by dst
__global__ void sort_kernel(const int* __restrict__ ei, int* __restrict__ woff,
                            int* __restrict__ es, int* __restrict__ ed){
  int e = blockIdx.x*blockDim.x + threadIdx.x;
  if (e < N_EDGES){
    int s = ei[e], d = ei[N_EDGES + e];
    int pos = atomicAdd(&woff[d], 1);
    es[pos] = s; ed[pos] = d;
  }
}

// Pack weight [K][N] fp32 -> fragment-ordered bf16: out[ks][ct][lane][8]
__global__ void pack_wfrag(const float* __restrict__ w, int K, int N, int nct,
                           unsigned short* __restrict__ out, int total){
  int i = blockIdx.x*blockDim.x + threadIdx.x;
  if (i >= total) return;
  int j  = i & 7;
  int l  = (i >> 3) & 63;
  int t  = i >> 9;
  int ct = t % nct, ks = t / nct;
  int n = ct*16 + (l & 15);
  int k = ks*32 + ((l >> 4) << 3) + j;
  float v = (k < K && n < N) ? w[(size_t)k*N + n] : 0.f;
  out[i] = f2bf(v);
}

// Pack W' = [W_top - W_bot | W_bot] from w1[2F][HID] into frag order, N'=640, K->KPAD
template<int F>
__global__ void pack_w1frag(const float* __restrict__ w1,
                            unsigned short* __restrict__ out, int total){
  int i = blockIdx.x*blockDim.x + threadIdx.x;
  if (i >= total) return;
  int j  = i & 7;
  int l  = (i >> 3) & 63;
  int t  = i >> 9;
  int ct = t % 40, ks = t / 40;
  int n = ct*16 + (l & 15);
  int k = ks*32 + ((l >> 4) << 3) + j;
  float v = 0.f;
  if (k < F){
    if (n < HIDP){ if (n < HID) v = w1[(size_t)k*HID + n] - w1[(size_t)(F+k)*HID + n]; }
    else { int nn = n - HIDP; if (nn < HID) v = w1[(size_t)(F+k)*HID + nn]; }
  }
  out[i] = f2bf(v);
}

__global__ void pad_bias(const float* __restrict__ b, int K, float* __restrict__ out){
  int i = blockIdx.x*blockDim.x + threadIdx.x;
  if (i < HIDP) out[i] = (i < K) ? b[i] : 0.f;
}

// x f32[N,16] -> xb bf16[N,32] zero-padded
__global__ void cvt_x0(const float* __restrict__ x, unsigned short* __restrict__ xb){
  int i = blockIdx.x*blockDim.x + threadIdx.x;
  if (i < N_NODES*32){
    int n = i >> 5, c = i & 31;
    xb[i] = (c < NODE_F) ? f2bf(x[(size_t)n*NODE_F + c]) : 0;
  }
}

// node-level GEMM: [64 x KPAD] @ [KPAD x 640] -> Ub|Vb bf16 (cols 0..319 | 320..639)
template<int KPAD>
__global__ __launch_bounds__(256) void node_gemm(
    const unsigned short* __restrict__ xb, const unsigned short* __restrict__ wf,
    unsigned short* __restrict__ Ub, unsigned short* __restrict__ Vb){
  constexpr int NCH = KPAD/8;
  __shared__ __align__(16) unsigned short at[NCH][ROWP][8];
  const int tid = threadIdx.x;
  const int n0 = blockIdx.x*64;
  for (int i = tid; i < 64*NCH; i += 256){
    int row = i / NCH, c = i % NCH;
    int n = n0 + row; if (n >= N_NODES) n = N_NODES-1;
    *(uint4*)&at[c][row][0] = *(const uint4*)&xb[(size_t)n*KPAD + c*8];
  }
  __syncthreads();
  const int wave = tid >> 6, l = tid & 63;
  const int lrow = l & 15, lq = l >> 4;
  f32x4 acc[4][10];
  #pragma unroll
  for (int rt = 0; rt < 4; ++rt)
    #pragma unroll
    for (int c = 0; c < 10; ++c)
      acc[rt][c] = (f32x4){0.f,0.f,0.f,0.f};
  for (int ks = 0; ks < KPAD/32; ++ks){
    bf16x8 a[4];
    #pragma unroll
    for (int rt = 0; rt < 4; ++rt)
      a[rt] = __builtin_bit_cast(bf16x8, *(const uint4*)&at[4*ks + lq][16*rt + lrow][0]);
    #pragma unroll
    for (int c = 0; c < 10; ++c){
      int ct = wave*10 + c;
      bf16x8 b = __builtin_bit_cast(bf16x8,
                   *(const uint4*)&wf[(((size_t)(ks*40 + ct)) << 9) + l*8]);
      #pragma unroll
      for (int rt = 0; rt < 4; ++rt)
        acc[rt][c] = __builtin_amdgcn_mfma_f32_16x16x32_bf16(a[rt], b, acc[rt][c], 0, 0, 0);
    }
  }
  #pragma unroll
  for (int c = 0; c < 10; ++c){
    int col = (wave*10 + c)*16 + lrow;
    #pragma unroll
    for (int rt = 0; rt < 4; ++rt){
      #pragma unroll
      for (int r = 0; r < 4; ++r){
        int n = n0 + rt*16 + lq*4 + r;
        if (n < N_NODES){
          unsigned short hv = f2bf_hw(acc[rt][c][r]);
          if (col < HIDP) Ub[(size_t)n*HIDP + col] = hv;
          else            Vb[(size_t)n*HIDP + col - HIDP] = hv;
        }
      }
    }
  }
}

// Per 64-edge tile (edges sorted by dst): gather h1 -> LDS chunked; GEMM1; h2; GEMM2;
// run-compressed atomic scatter.
__global__ __launch_bounds__(256, 3) void edge_mfma(
    const int* __restrict__ es, const int* __restrict__ ed,
    const unsigned short* __restrict__ U, const unsigned short* __restrict__ V,
    const float* __restrict__ b1p, const unsigned short* __restrict__ w2f,
    const float* __restrict__ b2p, const unsigned short* __restrict__ w3f,
    float* __restrict__ nodeacc){
  __shared__ __align__(16) unsigned short hs[HIDP/8][ROWP][8];
  __shared__ int sdst[EPB], ssrc[EPB];
  const int tid = threadIdx.x;
  const int e0 = blockIdx.x * EPB;
  if (tid < EPB){ ssrc[tid] = es[e0 + tid]; sdst[tid] = ed[e0 + tid]; }
  __syncthreads();

  // ---- gather + h1 ----
  #pragma unroll
  for (int it = 0; it < 10; ++it){
    int i = tid + it*256;
    int c = i >> 6, e = i & 63;
    const uint4 uu = *(const uint4*)&U[(size_t)sdst[e]*HIDP + c*8];
    const uint4 vv = *(const uint4*)&V[(size_t)ssrc[e]*HIDP + c*8];
    const float4 bl = *(const float4*)&b1p[c*8];
    const float4 bh = *(const float4*)&b1p[c*8 + 4];
    const unsigned int uarr[4] = {uu.x, uu.y, uu.z, uu.w};
    const unsigned int varr[4] = {vv.x, vv.y, vv.z, vv.w};
    const float barr[8] = {bl.x, bl.y, bl.z, bl.w, bh.x, bh.y, bh.z, bh.w};
    unsigned int ou[4];
    #pragma unroll
    for (int q = 0; q < 4; ++q){
      float f0 = relu_f(bf2f(uarr[q] & 0xFFFFu) + bf2f(varr[q] & 0xFFFFu) + barr[2*q]);
      float f1 = relu_f(bf2f(uarr[q] >> 16)     + bf2f(varr[q] >> 16)     + barr[2*q+1]);
      ou[q] = (unsigned int)f2bf_hw(f0) | ((unsigned int)f2bf_hw(f1) << 16);
    }
    *(uint4*)&hs[c][e][0] = make_uint4(ou[0], ou[1], ou[2], ou[3]);
  }
  __syncthreads();

  const int wave = tid >> 6, l = tid & 63;
  const int lrow = l & 15, lq = l >> 4;

  // ---- GEMM1: [64 x 320] = h1 @ w2 ----
  f32x4 acc1[4][5];
  #pragma unroll
  for (int rt = 0; rt < 4; ++rt)
    #pragma unroll
    for (int c = 0; c < 5; ++c)
      acc1[rt][c] = (f32x4){0.f,0.f,0.f,0.f};
  for (int ks = 0; ks < NKS; ++ks){
    bf16x8 a[4];
    #pragma unroll
    for (int rt = 0; rt < 4; ++rt)
      a[rt] = __builtin_bit_cast(bf16x8, *(const uint4*)&hs[4*ks + lq][16*rt + lrow][0]);
    #pragma unroll
    for (int c = 0; c < 5; ++c){
      int ct = wave*5 + c;
      bf16x8 b = __builtin_bit_cast(bf16x8,
                   *(const uint4*)&w2f[(((size_t)(ks*NCT1 + ct)) << 9) + l*8]);
      #pragma unroll
      for (int rt = 0; rt < 4; ++rt)
        acc1[rt][c] = __builtin_amdgcn_mfma_f32_16x16x32_bf16(a[rt], b, acc1[rt][c], 0, 0, 0);
    }
  }
  __syncthreads();

  // ---- epilogue1: h2 = relu(C1 + b2) -> hs ----
  #pragma unroll
  for (int c = 0; c < 5; ++c){
    int col = (wave*5 + c)*16 + lrow;
    float b2v = b2p[col];
    #pragma unroll
    for (int rt = 0; rt < 4; ++rt){
      #pragma unroll
      for (int r = 0; r < 4; ++r){
        int row = rt*16 + lq*4 + r;
        hs[col >> 3][row][col & 7] = f2bf_hw(relu_f(acc1[rt][c][r] + b2v));
      }
    }
  }
  __syncthreads();

  // ---- GEMM2: [64 x 128] = h2 @ w3 ----
  f32x4 acc2[4][2];
  #pragma unroll
  for (int rt = 0; rt < 4; ++rt)
    #pragma unroll
    for (int c = 0; c < 2; ++c)
      acc2[rt][c] = (f32x4){0.f,0.f,0.f,0.f};
  for (int ks = 0; ks < NKS; ++ks){
    bf16x8 a[4];
    #pragma unroll
    for (int rt = 0; rt < 4; ++rt)
      a[rt] = __builtin_bit_cast(bf16x8, *(const uint4*)&hs[4*ks + lq][16*rt + lrow][0]);
    #pragma unroll
    for (int c = 0; c < 2; ++c){
      int ct = wave*2 + c;
      bf16x8 b = __builtin_bit_cast(bf16x8,
                   *(const uint4*)&w3f[(((size_t)(ks*NCT2 + ct)) << 9) + l*8]);
      #pragma unroll
      for (int rt = 0; rt < 4; ++rt)
        acc2[rt][c] = __builtin_amdgcn_mfma_f32_16x16x32_bf16(a[rt], b, acc2[rt][c], 0, 0, 0);
    }
  }

  // ---- scatter-add with run compression over 4 consecutive (sorted) rows ----
  #pragma unroll
  for (int c = 0; c < 2; ++c){
    int col = (wave*2 + c)*16 + lrow;
    if (col < LAT){
      #pragma unroll
      for (int rt = 0; rt < 4; ++rt){
        int base = rt*16 + lq*4;
        int prev = sdst[base];
        float runv = acc2[rt][c][0];
        #pragma unroll
        for (int r = 1; r < 4; ++r){
          int d = sdst[base + r];
          float v = acc2[rt][c][r];
          if (d == prev) runv += v;
          else {
            atomicAdd(&nodeacc[(size_t)prev*LAT + col], runv);
            prev = d; runv = v;
          }
        }
        atomicAdd(&nodeacc[(size_t)prev*LAT + col], runv);
      }
    }
  }
}

// x1b[n][j<100] = bf16(relu(acc/max(cnt,1) + (cnt>0?b3:0))), pad cols 100..127 = 0;
// re-zero nodeacc.
__global__ void finalize_kernel(float* __restrict__ nodeacc, const int* __restrict__ hist,
                                const float* __restrict__ b3,
                                unsigned short* __restrict__ x1b){
  int idx = blockIdx.x*blockDim.x + threadIdx.x;
  if (idx < N_NODES*128){
    int n = idx >> 7, j = idx & 127;
    unsigned short o = 0;
    if (j < LAT){
      int c = hist[n];
      float v = nodeacc[(size_t)n*LAT + j] / fmaxf((float)c, 1.f);
      v += (c > 0) ? b3[j] : 0.f;
      o = f2bf_hw(relu_f(v));
      nodeacc[(size_t)n*LAT + j] = 0.f;
    }
    x1b[idx] = o;
  }
}

__global__ void pool_kernel(const unsigned short* __restrict__ x1b,
                            const int* __restrict__ batch,
                            float* __restrict__ gacc, float* __restrict__ gcnt){
  int idx = blockIdx.x*blockDim.x + threadIdx.x;
  if (idx < N_NODES*LAT){
    int n = idx / LAT, j = idx - n*LAT;
    int g = batch[n];
    atomicAdd(&gacc[g*LAT + j], bf2f(x1b[(size_t)n*128 + j]));
    if (j == 0) atomicAdd(&gcnt[g], 1.f);
  }
}

__global__ __launch_bounds__(128) void head_kernel(
    const float* __restrict__ gacc, const float* __restrict__ gcnt,
    const float* __restrict__ u,
    const float* __restrict__ w1, const float* __restrict__ bb1,
    const float* __restrict__ w2, const float* __restrict__ bb2,
    const float* __restrict__ w3, const float* __restrict__ bb3,
    float* __restrict__ out){
  __shared__ float p[N_GRAPHS][LAT+GLOBAL_F];
  __shared__ float h1[N_GRAPHS][LAT];
  __shared__ float h2[N_GRAPHS][LAT];
  const int tid = threadIdx.x;
  for (int t = tid; t < N_GRAPHS*LAT; t += 128){
    int g = t / LAT, k = t - g*LAT;
    p[g][k] = gacc[t] / fmaxf(gcnt[g], 1.f);
  }
  for (int t = tid; t < N_GRAPHS*GLOBAL_F; t += 128){
    int g = t / GLOBAL_F, c = t - g*GLOBAL_F;
    p[g][LAT + c] = u[t];
  }
  __syncthreads();
  for (int t = tid; t < N_GRAPHS*LAT; t += 128){
    int g = t / LAT, j = t - g*LAT;
    float s = bb1[j];
    for (int k = 0; k < LAT+GLOBAL_F; k++) s += p[g][k]*w1[(size_t)k*LAT + j];
    h1[g][j] = relu_f(s);
  }
  __syncthreads();
  for (int t = tid; t < N_GRAPHS*LAT; t += 128){
    int g = t / LAT, j = t - g*LAT;
    float s = bb2[j];
    for (int k = 0; k < LAT; k++) s += h1[g][k]*w2[(size_t)k*LAT + j];
    h2[g][j] = relu_f(s);
  }
  __syncthreads();
  for (int t = tid; t < N_GRAPHS; t += 128){
    float s = bb3[0];
    for (int k = 0; k < LAT; k++) s += h2[t][k]*w3[k];
    out[t] = s;
  }
}

extern "C" void kernel_launch(void* const* d_in, const int* in_sizes, int n_in,
                              void* d_out, int out_size, void* d_ws, size_t ws_size,
                              hipStream_t stream){
  (void)in_sizes; (void)n_in; (void)out_size; (void)ws_size;
  const float* x     = (const float*)d_in[0];
  const int*   ei    = (const int*)d_in[1];
  const int*   batch = (const int*)d_in[2];
  const float* u     = (const float*)d_in[3];
  const float* l0_w1 = (const float*)d_in[4];  const float* l0_b1 = (const float*)d_in[5];
  const float* l0_w2 = (const float*)d_in[6];  const float* l0_b2 = (const float*)d_in[7];
  const float* l0_w3 = (const float*)d_in[8];  const float* l0_b3 = (const float*)d_in[9];
  const float* l1_w1 = (const float*)d_in[10]; const float* l1_b1 = (const float*)d_in[11];
  const float* l1_w2 = (const float*)d_in[12]; const float* l1_b2 = (const float*)d_in[13];
  const float* l1_w3 = (const float*)d_in[14]; const float* l1_b3 = (const float*)d_in[15];
  const float* lin_w1= (const float*)d_in[16]; const float* lin_b1= (const float*)d_in[17];
  const float* lin_w2= (const float*)d_in[18]; const float* lin_b2= (const float*)d_in[19];
  const float* lin_w3= (const float*)d_in[20]; const float* lin_b3= (const float*)d_in[21];

  char* wsb = (char*)d_ws;
  const size_t UV_BYTES  = (size_t)N_NODES*HIDP*sizeof(unsigned short);
  const size_t W2F_ELEMS = (size_t)NKS*NCT1*512;    // 102400
  const size_t W3F_ELEMS = (size_t)NKS*NCT2*512;    // 40960
  const size_t W1F0_ELEMS = (size_t)(32/32)*40*512; // 20480
  const size_t W1F1_ELEMS = (size_t)(128/32)*40*512;// 81920

  unsigned short* Ub   = (unsigned short*)wsb;  wsb += UV_BYTES;
  unsigned short* Vb   = (unsigned short*)wsb;  wsb += UV_BYTES;
  unsigned short* w2f0 = (unsigned short*)wsb;  wsb += W2F_ELEMS*2;
  unsigned short* w3f0 = (unsigned short*)wsb;  wsb += W3F_ELEMS*2;
  unsigned short* w2f1 = (unsigned short*)wsb;  wsb += W2F_ELEMS*2;
  unsigned short* w3f1 = (unsigned short*)wsb;  wsb += W3F_ELEMS*2;
  unsigned short* w1f0 = (unsigned short*)wsb;  wsb += W1F0_ELEMS*2;
  unsigned short* w1f1 = (unsigned short*)wsb;  wsb += W1F1_ELEMS*2;
  float* b1p0 = (float*)wsb;                    wsb += HIDP*4;
  float* b2p0 = (float*)wsb;                    wsb += HIDP*4;
  float* b1p1 = (float*)wsb;                    wsb += HIDP*4;
  float* b2p1 = (float*)wsb;                    wsb += HIDP*4;
  unsigned short* xb0 = (unsigned short*)wsb;   wsb += (size_t)N_NODES*32*2;
  unsigned short* x1b = (unsigned short*)wsb;   wsb += (size_t)N_NODES*128*2;
  // contiguous zero region: nodeacc + gacc + gcnt + hist
  float* nodeacc = (float*)wsb;                 wsb += (size_t)N_NODES*LAT*4;
  float* gacc    = (float*)wsb;                 wsb += (size_t)N_GRAPHS*LAT*4;
  float* gcnt    = (float*)wsb;                 wsb += (size_t)N_GRAPHS*4;
  int*   hist    = (int*)wsb;                   wsb += (size_t)N_NODES*4;
  int*   woff    = (int*)wsb;                   wsb += (size_t)N_NODES*4;
  int*   es      = (int*)wsb;                   wsb += (size_t)N_EDGES*4;
  int*   ed      = (int*)wsb;                   wsb += (size_t)N_EDGES*4;

  {
    int zn = N_NODES*LAT + N_GRAPHS*LAT + N_GRAPHS + N_NODES;
    hipLaunchKernelGGL(zero_kernel, dim3((zn+255)/256), dim3(256), 0, stream, nodeacc, zn);
  }
  hipLaunchKernelGGL(hist_kernel, dim3((N_EDGES+255)/256), dim3(256), 0, stream, ei, hist);
  hipLaunchKernelGGL(scan_kernel, dim3(1), dim3(256), 0, stream, hist, woff);
  hipLaunchKernelGGL(sort_kernel, dim3((N_EDGES+255)/256), dim3(256), 0, stream,
                     ei, woff, es, ed);

  // weight / bias prep
  hipLaunchKernelGGL(pack_wfrag, dim3((W2F_ELEMS+255)/256), dim3(256), 0, stream,
                     l0_w2, HID, HID, NCT1, w2f0, (int)W2F_ELEMS);
  hipLaunchKernelGGL(pack_wfrag, dim3((W3F_ELEMS+255)/256), dim3(256), 0, stream,
                     l0_w3, HID, LAT, NCT2, w3f0, (int)W3F_ELEMS);
  hipLaunchKernelGGL(pack_wfrag, dim3((W2F_ELEMS+255)/256), dim3(256), 0, stream,
                     l1_w2, HID, HID, NCT1, w2f1, (int)W2F_ELEMS);
  hipLaunchKernelGGL(pack_wfrag, dim3((W3F_ELEMS+255)/256), dim3(256), 0, stream,
                     l1_w3, HID, LAT, NCT2, w3f1, (int)W3F_ELEMS);
  hipLaunchKernelGGL(pack_w1frag<NODE_F>, dim3((W1F0_ELEMS+255)/256), dim3(256), 0, stream,
                     l0_w1, w1f0, (int)W1F0_ELEMS);
  hipLaunchKernelGGL(pack_w1frag<LAT>, dim3((W1F1_ELEMS+255)/256), dim3(256), 0, stream,
                     l1_w1, w1f1, (int)W1F1_ELEMS);
  hipLaunchKernelGGL(pad_bias, dim3(2), dim3(256), 0, stream, l0_b1, HID, b1p0);
  hipLaunchKernelGGL(pad_bias, dim3(2), dim3(256), 0, stream, l0_b2, HID, b2p0);
  hipLaunchKernelGGL(pad_bias, dim3(2), dim3(256), 0, stream, l1_b1, HID, b1p1);
  hipLaunchKernelGGL(pad_bias, dim3(2), dim3(256), 0, stream, l1_b2, HID, b2p1);
  hipLaunchKernelGGL(cvt_x0, dim3((N_NODES*32+255)/256), dim3(256), 0, stream, x, xb0);

  const int NGB = (N_NODES + 63)/64;  // 782

  // layer 0
  hipLaunchKernelGGL(node_gemm<32>, dim3(NGB), dim3(256), 0, stream, xb0, w1f0, Ub, Vb);
  hipLaunchKernelGGL(edge_mfma, dim3(N_EDGES/EPB), dim3(256), 0, stream,
                     es, ed, Ub, Vb, b1p0, w2f0, b2p0, w3f0, nodeacc);
  hipLaunchKernelGGL(finalize_kernel, dim3((N_NODES*128+255)/256), dim3(256), 0, stream,
                     nodeacc, hist, l0_b3, x1b);

  // layer 1
  hipLaunchKernelGGL(node_gemm<128>, dim3(NGB), dim3(256), 0, stream, x1b, w1f1, Ub, Vb);
  hipLaunchKernelGGL(edge_mfma, dim3(N_EDGES/EPB), dim3(256), 0, stream,
                     es, ed, Ub, Vb, b1p1, w2f1, b2p1, w3f1, nodeacc);
  hipLaunchKernelGGL(finalize_kernel, dim3((N_NODES*128+255)/256), dim3(256), 0, stream,
                     nodeacc, hist, l1_b3, x1b);

  // pooling + head
  hipLaunchKernelGGL(pool_kernel, dim3((N_NODES*LAT+255)/256), dim3(256), 0, stream,
                     x1b, batch, gacc, gcnt);
  hipLaunchKernelGGL(head_kernel, dim3(1), dim3(128), 0, stream,
                     gacc, gcnt, u, lin_w1, lin_b1, lin_w2, lin_b2, lin_w3, lin_b3,
                     (float*)d_out);
}

// Round 4
// 1546.523 us; speedup vs baseline: 9.6474x; 1.2557x over previous
//
#include <hip/hip_runtime.h>
#include <cstdint>
#include <cstddef>

#define N_NODES  50000
#define N_GRAPHS 32
#define NODE_F   16
#define GLOBAL_F 2
#define HID      300
#define LAT      100
#define N_EDGES  800000

#define HIDP 320            // padded K / hidden (multiple of 32)
#define LATP 128            // padded GEMM2 output cols
#define NCT1 (HIDP/16)      // 20 col-tiles GEMM1
#define NCT2 (LATP/16)      // 8  col-tiles GEMM2
#define NKS  (HIDP/32)      // 10 k-steps
#define EPB  64             // edges per block
#define ROWP 66             // padded row count in chunked LDS layout

typedef __bf16 bf16x8 __attribute__((ext_vector_type(8)));
typedef float  f32x4  __attribute__((ext_vector_type(4)));

__device__ __forceinline__ float relu_f(float x){ return fmaxf(x, 0.f); }

__device__ __forceinline__ unsigned short f2bf(float x){   // RNE, for prep kernels
  unsigned int u = __float_as_uint(x);
  u = (u + 0x7FFFu + ((u >> 16) & 1u)) >> 16;
  return (unsigned short)u;
}
__device__ __forceinline__ unsigned short f2bf_hw(float x){ // hot path: hw convert
  __bf16 h = (__bf16)x;
  return __builtin_bit_cast(unsigned short, h);
}
__device__ __forceinline__ float bf2f(unsigned int h){
  return __uint_as_float(h << 16);
}

__global__ void zero_kernel(float* __restrict__ p, int n){
  int i = blockIdx.x*blockDim.x + threadIdx.x;
  if (i < n) p[i] = 0.f;
}

__global__ void hist_kernel(const int* __restrict__ ei, int* __restrict__ hist){
  int e = blockIdx.x*blockDim.x + threadIdx.x;
  if (e < N_EDGES) atomicAdd(&hist[ei[N_EDGES + e]], 1);
}

// single-block exclusive scan of hist -> woff (write cursor per node)
__global__ __launch_bounds__(256) void scan_kernel(const int* __restrict__ hist,
                                                   int* __restrict__ woff){
  __shared__ int part[256];
  const int t = threadIdx.x;
  const int CH = (N_NODES + 255) / 256;
  const int lo = t*CH, hi = (lo + CH < N_NODES) ? lo + CH : N_NODES;
  int s = 0;
  for (int i = lo; i < hi; ++i) s += hist[i];
  part[t] = s;
  __syncthreads();
  for (int d = 1; d < 256; d <<= 1){
    int v = (t >= d) ? part[t-d] : 0;
    __syncthreads();
    part[t] += v;
    __syncthreads();
  }
  int run = (t == 0) ? 0 : part[t-1];
  for (int i = lo; i < hi; ++i){ woff[i] = run; run += hist[i]; }
}

// counting-sort scatter: edges grouped by dst
__global__ void sort_kernel(const int* __restrict__ ei, int* __restrict__ woff,
                            int* __restrict__ es, int* __restrict__ ed){
  int e = blockIdx.x*blockDim.x + threadIdx.x;
  if (e < N_EDGES){
    int s = ei[e], d = ei[N_EDGES + e];
    int pos = atomicAdd(&woff[d], 1);
    es[pos] = s; ed[pos] = d;
  }
}

// graph start offsets from sorted batch: gstart[g] = first n with batch[n] >= g
__global__ void gstart_kernel(const int* __restrict__ batch, int* __restrict__ gstart){
  int n = blockIdx.x*blockDim.x + threadIdx.x;
  if (n < N_NODES){
    int b = batch[n];
    if (n == 0){ for (int g = 0; g <= b; ++g) gstart[g] = 0; }
    else {
      int bp = batch[n-1];
      for (int g = bp+1; g <= b; ++g) gstart[g] = n;
    }
    if (n == N_NODES-1){ for (int g = b+1; g <= N_GRAPHS; ++g) gstart[g] = N_NODES; }
  }
}

// Pack weight [K][N] fp32 -> fragment-ordered bf16: out[ks][ct][lane][8]
__global__ void pack_wfrag(const float* __restrict__ w, int K, int N, int nct,
                           unsigned short* __restrict__ out, int total){
  int i = blockIdx.x*blockDim.x + threadIdx.x;
  if (i >= total) return;
  int j  = i & 7;
  int l  = (i >> 3) & 63;
  int t  = i >> 9;
  int ct = t % nct, ks = t / nct;
  int n = ct*16 + (l & 15);
  int k = ks*32 + ((l >> 4) << 3) + j;
  float v = (k < K && n < N) ? w[(size_t)k*N + n] : 0.f;
  out[i] = f2bf(v);
}

// Pack W' = [W_top - W_bot | W_bot] from w1[2F][HID] into frag order, N'=640
template<int F>
__global__ void pack_w1frag(const float* __restrict__ w1,
                            unsigned short* __restrict__ out, int total){
  int i = blockIdx.x*blockDim.x + threadIdx.x;
  if (i >= total) return;
  int j  = i & 7;
  int l  = (i >> 3) & 63;
  int t  = i >> 9;
  int ct = t % 40, ks = t / 40;
  int n = ct*16 + (l & 15);
  int k = ks*32 + ((l >> 4) << 3) + j;
  float v = 0.f;
  if (k < F){
    if (n < HIDP){ if (n < HID) v = w1[(size_t)k*HID + n] - w1[(size_t)(F+k)*HID + n]; }
    else { int nn = n - HIDP; if (nn < HID) v = w1[(size_t)(F+k)*HID + nn]; }
  }
  out[i] = f2bf(v);
}

// all four padded biases in one launch
__global__ void pad_bias4(const float* __restrict__ a0, const float* __restrict__ a1,
                          const float* __restrict__ a2, const float* __restrict__ a3,
                          float* __restrict__ o0, float* __restrict__ o1,
                          float* __restrict__ o2, float* __restrict__ o3){
  int i = blockIdx.x*blockDim.x + threadIdx.x;
  if (i < HIDP){
    float v0 = (i < HID) ? a0[i] : 0.f;
    float v1 = (i < HID) ? a1[i] : 0.f;
    float v2 = (i < HID) ? a2[i] : 0.f;
    float v3 = (i < HID) ? a3[i] : 0.f;
    o0[i] = v0; o1[i] = v1; o2[i] = v2; o3[i] = v3;
  }
}

// x f32[N,16] -> xb bf16[N,32] zero-padded
__global__ void cvt_x0(const float* __restrict__ x, unsigned short* __restrict__ xb){
  int i = blockIdx.x*blockDim.x + threadIdx.x;
  if (i < N_NODES*32){
    int n = i >> 5, c = i & 31;
    xb[i] = (c < NODE_F) ? f2bf(x[(size_t)n*NODE_F + c]) : 0;
  }
}

// node-level GEMM: [64 x KPAD] @ [KPAD x 640] -> Ub|Vb bf16
template<int KPAD>
__global__ __launch_bounds__(256) void node_gemm(
    const unsigned short* __restrict__ xb, const unsigned short* __restrict__ wf,
    unsigned short* __restrict__ Ub, unsigned short* __restrict__ Vb){
  constexpr int NCH = KPAD/8;
  __shared__ __align__(16) unsigned short at[NCH][ROWP][8];
  const int tid = threadIdx.x;
  const int n0 = blockIdx.x*64;
  for (int i = tid; i < 64*NCH; i += 256){
    int row = i / NCH, c = i % NCH;
    int n = n0 + row; if (n >= N_NODES) n = N_NODES-1;
    *(uint4*)&at[c][row][0] = *(const uint4*)&xb[(size_t)n*KPAD + c*8];
  }
  __syncthreads();
  const int wave = tid >> 6, l = tid & 63;
  const int lrow = l & 15, lq = l >> 4;
  f32x4 acc[4][10];
  #pragma unroll
  for (int rt = 0; rt < 4; ++rt)
    #pragma unroll
    for (int c = 0; c < 10; ++c)
      acc[rt][c] = (f32x4){0.f,0.f,0.f,0.f};
  for (int ks = 0; ks < KPAD/32; ++ks){
    bf16x8 a[4];
    #pragma unroll
    for (int rt = 0; rt < 4; ++rt)
      a[rt] = __builtin_bit_cast(bf16x8, *(const uint4*)&at[4*ks + lq][16*rt + lrow][0]);
    #pragma unroll
    for (int c = 0; c < 10; ++c){
      int ct = wave*10 + c;
      bf16x8 b = __builtin_bit_cast(bf16x8,
                   *(const uint4*)&wf[(((size_t)(ks*40 + ct)) << 9) + l*8]);
      #pragma unroll
      for (int rt = 0; rt < 4; ++rt)
        acc[rt][c] = __builtin_amdgcn_mfma_f32_16x16x32_bf16(a[rt], b, acc[rt][c], 0, 0, 0);
    }
  }
  #pragma unroll
  for (int c = 0; c < 10; ++c){
    int col = (wave*10 + c)*16 + lrow;
    #pragma unroll
    for (int rt = 0; rt < 4; ++rt){
      #pragma unroll
      for (int r = 0; r < 4; ++r){
        int n = n0 + rt*16 + lq*4 + r;
        if (n < N_NODES){
          unsigned short hv = f2bf_hw(acc[rt][c][r]);
          if (col < HIDP) Ub[(size_t)n*HIDP + col] = hv;
          else            Vb[(size_t)n*HIDP + col - HIDP] = hv;
        }
      }
    }
  }
}

// Per 64-edge tile (edges sorted by dst): gather h1 -> LDS chunked; GEMM1; h2; GEMM2;
// run-compressed atomic scatter.
__global__ __launch_bounds__(256, 3) void edge_mfma(
    const int* __restrict__ es, const int* __restrict__ ed,
    const unsigned short* __restrict__ U, const unsigned short* __restrict__ V,
    const float* __restrict__ b1p, const unsigned short* __restrict__ w2f,
    const float* __restrict__ b2p, const unsigned short* __restrict__ w3f,
    float* __restrict__ nodeacc){
  __shared__ __align__(16) unsigned short hs[HIDP/8][ROWP][8];
  __shared__ int sdst[EPB];
  const int tid = threadIdx.x;
  const int e0 = blockIdx.x * EPB;
  // each thread's gather edge is tid&63 for every iteration -> load straight from global
  const int eL = tid & 63;
  const int mysrc = es[e0 + eL];
  const int mydst = ed[e0 + eL];
  if (tid < EPB) sdst[tid] = ed[e0 + tid];   // visible after first __syncthreads

  // ---- gather + h1 ----
  const size_t ubase = (size_t)mydst*HIDP;
  const size_t vbase = (size_t)mysrc*HIDP;
  #pragma unroll
  for (int it = 0; it < 10; ++it){
    int c = (tid + it*256) >> 6;
    const uint4 uu = *(const uint4*)&U[ubase + c*8];
    const uint4 vv = *(const uint4*)&V[vbase + c*8];
    const float4 bl = *(const float4*)&b1p[c*8];
    const float4 bh = *(const float4*)&b1p[c*8 + 4];
    const unsigned int uarr[4] = {uu.x, uu.y, uu.z, uu.w};
    const unsigned int varr[4] = {vv.x, vv.y, vv.z, vv.w};
    const float barr[8] = {bl.x, bl.y, bl.z, bl.w, bh.x, bh.y, bh.z, bh.w};
    unsigned int ou[4];
    #pragma unroll
    for (int q = 0; q < 4; ++q){
      float f0 = relu_f(bf2f(uarr[q] & 0xFFFFu) + bf2f(varr[q] & 0xFFFFu) + barr[2*q]);
      float f1 = relu_f(bf2f(uarr[q] >> 16)     + bf2f(varr[q] >> 16)     + barr[2*q+1]);
      ou[q] = (unsigned int)f2bf_hw(f0) | ((unsigned int)f2bf_hw(f1) << 16);
    }
    *(uint4*)&hs[c][eL][0] = make_uint4(ou[0], ou[1], ou[2], ou[3]);
  }
  __syncthreads();

  const int wave = tid >> 6, l = tid & 63;
  const int lrow = l & 15, lq = l >> 4;

  // ---- GEMM1: [64 x 320] = h1 @ w2 ----
  f32x4 acc1[4][5];
  #pragma unroll
  for (int rt = 0; rt < 4; ++rt)
    #pragma unroll
    for (int c = 0; c < 5; ++c)
      acc1[rt][c] = (f32x4){0.f,0.f,0.f,0.f};
  for (int ks = 0; ks < NKS; ++ks){
    bf16x8 a[4];
    #pragma unroll
    for (int rt = 0; rt < 4; ++rt)
      a[rt] = __builtin_bit_cast(bf16x8, *(const uint4*)&hs[4*ks + lq][16*rt + lrow][0]);
    #pragma unroll
    for (int c = 0; c < 5; ++c){
      int ct = wave*5 + c;
      bf16x8 b = __builtin_bit_cast(bf16x8,
                   *(const uint4*)&w2f[(((size_t)(ks*NCT1 + ct)) << 9) + l*8]);
      #pragma unroll
      for (int rt = 0; rt < 4; ++rt)
        acc1[rt][c] = __builtin_amdgcn_mfma_f32_16x16x32_bf16(a[rt], b, acc1[rt][c], 0, 0, 0);
    }
  }
  __syncthreads();

  // ---- epilogue1: h2 = relu(C1 + b2) -> hs ----
  #pragma unroll
  for (int c = 0; c < 5; ++c){
    int col = (wave*5 + c)*16 + lrow;
    float b2v = b2p[col];
    #pragma unroll
    for (int rt = 0; rt < 4; ++rt){
      #pragma unroll
      for (int r = 0; r < 4; ++r){
        int row = rt*16 + lq*4 + r;
        hs[col >> 3][row][col & 7] = f2bf_hw(relu_f(acc1[rt][c][r] + b2v));
      }
    }
  }
  __syncthreads();

  // ---- GEMM2: [64 x 128] = h2 @ w3 ----
  f32x4 acc2[4][2];
  #pragma unroll
  for (int rt = 0; rt < 4; ++rt)
    #pragma unroll
    for (int c = 0; c < 2; ++c)
      acc2[rt][c] = (f32x4){0.f,0.f,0.f,0.f};
  for (int ks = 0; ks < NKS; ++ks){
    bf16x8 a[4];
    #pragma unroll
    for (int rt = 0; rt < 4; ++rt)
      a[rt] = __builtin_bit_cast(bf16x8, *(const uint4*)&hs[4*ks + lq][16*rt + lrow][0]);
    #pragma unroll
    for (int c = 0; c < 2; ++c){
      int ct = wave*2 + c;
      bf16x8 b = __builtin_bit_cast(bf16x8,
                   *(const uint4*)&w3f[(((size_t)(ks*NCT2 + ct)) << 9) + l*8]);
      #pragma unroll
      for (int rt = 0; rt < 4; ++rt)
        acc2[rt][c] = __builtin_amdgcn_mfma_f32_16x16x32_bf16(a[rt], b, acc2[rt][c], 0, 0, 0);
    }
  }

  // ---- scatter-add with run compression over 4 consecutive (sorted) rows ----
  #pragma unroll
  for (int c = 0; c < 2; ++c){
    int col = (wave*2 + c)*16 + lrow;
    if (col < LAT){
      #pragma unroll
      for (int rt = 0; rt < 4; ++rt){
        int base = rt*16 + lq*4;
        int prev = sdst[base];
        float runv = acc2[rt][c][0];
        #pragma unroll
        for (int r = 1; r < 4; ++r){
          int d = sdst[base + r];
          float v = acc2[rt][c][r];
          if (d == prev) runv += v;
          else {
            atomicAdd(&nodeacc[(size_t)prev*LAT + col], runv);
            prev = d; runv = v;
          }
        }
        atomicAdd(&nodeacc[(size_t)prev*LAT + col], runv);
      }
    }
  }
}

// x1b[n][j<100] = bf16(relu(acc/max(cnt,1) + (cnt>0?b3:0))), pad cols -> 0; re-zero acc.
__global__ void finalize_kernel(float* __restrict__ nodeacc, const int* __restrict__ hist,
                                const float* __restrict__ b3,
                                unsigned short* __restrict__ x1b){
  int idx = blockIdx.x*blockDim.x + threadIdx.x;
  if (idx < N_NODES*128){
    int n = idx >> 7, j = idx & 127;
    unsigned short o = 0;
    if (j < LAT){
      int c = hist[n];
      float v = nodeacc[(size_t)n*LAT + j] / fmaxf((float)c, 1.f);
      v += (c > 0) ? b3[j] : 0.f;
      o = f2bf_hw(relu_f(v));
      nodeacc[(size_t)n*LAT + j] = 0.f;
    }
    x1b[idx] = o;
  }
}

// segmented mean-pool: one block per graph, no atomics; writes divided mean
__global__ __launch_bounds__(512) void pool_seg(const unsigned short* __restrict__ x1b,
                                                const int* __restrict__ gstart,
                                                float* __restrict__ pooled){
  __shared__ float buf[3][128];
  const int g = blockIdx.x;
  const int lo = gstart[g], hi = gstart[g+1];
  const int col = threadIdx.x & 127, q = threadIdx.x >> 7;
  float s = 0.f;
  for (int n = lo + q; n < hi; n += 4) s += bf2f(x1b[(size_t)n*128 + col]);
  if (q) buf[q-1][col] = s;
  __syncthreads();
  if (q == 0 && col < LAT){
    float tot = s + buf[0][col] + buf[1][col] + buf[2][col];
    pooled[g*LAT + col] = tot / fmaxf((float)(hi - lo), 1.f);
  }
}

__global__ __launch_bounds__(128) void head_kernel(
    const float* __restrict__ pooled,
    const float* __restrict__ u,
    const float* __restrict__ w1, const float* __restrict__ bb1,
    const float* __restrict__ w2, const float* __restrict__ bb2,
    const float* __restrict__ w3, const float* __restrict__ bb3,
    float* __restrict__ out){
  __shared__ float p[N_GRAPHS][LAT+GLOBAL_F];
  __shared__ float h1[N_GRAPHS][LAT];
  __shared__ float h2[N_GRAPHS][LAT];
  const int tid = threadIdx.x;
  for (int t = tid; t < N_GRAPHS*LAT; t += 128){
    int g = t / LAT, k = t - g*LAT;
    p[g][k] = pooled[t];
  }
  for (int t = tid; t < N_GRAPHS*GLOBAL_F; t += 128){
    int g = t / GLOBAL_F, c = t - g*GLOBAL_F;
    p[g][LAT + c] = u[t];
  }
  __syncthreads();
  for (int t = tid; t < N_GRAPHS*LAT; t += 128){
    int g = t / LAT, j = t - g*LAT;
    float s = bb1[j];
    for (int k = 0; k < LAT+GLOBAL_F; k++) s += p[g][k]*w1[(size_t)k*LAT + j];
    h1[g][j] = relu_f(s);
  }
  __syncthreads();
  for (int t = tid; t < N_GRAPHS*LAT; t += 128){
    int g = t / LAT, j = t - g*LAT;
    float s = bb2[j];
    for (int k = 0; k < LAT; k++) s += h1[g][k]*w2[(size_t)k*LAT + j];
    h2[g][j] = relu_f(s);
  }
  __syncthreads();
  for (int t = tid; t < N_GRAPHS; t += 128){
    float s = bb3[0];
    for (int k = 0; k < LAT; k++) s += h2[t][k]*w3[k];
    out[t] = s;
  }
}

extern "C" void kernel_launch(void* const* d_in, const int* in_sizes, int n_in,
                              void* d_out, int out_size, void* d_ws, size_t ws_size,
                              hipStream_t stream){
  (void)in_sizes; (void)n_in; (void)out_size; (void)ws_size;
  const float* x     = (const float*)d_in[0];
  const int*   ei    = (const int*)d_in[1];
  const int*   batch = (const int*)d_in[2];
  const float* u     = (const float*)d_in[3];
  const float* l0_w1 = (const float*)d_in[4];  const float* l0_b1 = (const float*)d_in[5];
  const float* l0_w2 = (const float*)d_in[6];  const float* l0_b2 = (const float*)d_in[7];
  const float* l0_w3 = (const float*)d_in[8];  const float* l0_b3 = (const float*)d_in[9];
  const float* l1_w1 = (const float*)d_in[10]; const float* l1_b1 = (const float*)d_in[11];
  const float* l1_w2 = (const float*)d_in[12]; const float* l1_b2 = (const float*)d_in[13];
  const float* l1_w3 = (const float*)d_in[14]; const float* l1_b3 = (const float*)d_in[15];
  const float* lin_w1= (const float*)d_in[16]; const float* lin_b1= (const float*)d_in[17];
  const float* lin_w2= (const float*)d_in[18]; const float* lin_b2= (const float*)d_in[19];
  const float* lin_w3= (const float*)d_in[20]; const float* lin_b3= (const float*)d_in[21];

  char* wsb = (char*)d_ws;
  const size_t UV_BYTES  = (size_t)N_NODES*HIDP*sizeof(unsigned short);
  const size_t W2F_ELEMS = (size_t)NKS*NCT1*512;
  const size_t W3F_ELEMS = (size_t)NKS*NCT2*512;
  const size_t W1F0_ELEMS = (size_t)1*40*512;
  const size_t W1F1_ELEMS = (size_t)4*40*512;

  unsigned short* Ub   = (unsigned short*)wsb;  wsb += UV_BYTES;
  unsigned short* Vb   = (unsigned short*)wsb;  wsb += UV_BYTES;
  unsigned short* w2f0 = (unsigned short*)wsb;  wsb += W2F_ELEMS*2;
  unsigned short* w3f0 = (unsigned short*)wsb;  wsb += W3F_ELEMS*2;
  unsigned short* w2f1 = (unsigned short*)wsb;  wsb += W2F_ELEMS*2;
  unsigned short* w3f1 = (unsigned short*)wsb;  wsb += W3F_ELEMS*2;
  unsigned short* w1f0 = (unsigned short*)wsb;  wsb += W1F0_ELEMS*2;
  unsigned short* w1f1 = (unsigned short*)wsb;  wsb += W1F1_ELEMS*2;
  float* b1p0 = (float*)wsb;                    wsb += HIDP*4;
  float* b2p0 = (float*)wsb;                    wsb += HIDP*4;
  float* b1p1 = (float*)wsb;                    wsb += HIDP*4;
  float* b2p1 = (float*)wsb;                    wsb += HIDP*4;
  unsigned short* xb0 = (unsigned short*)wsb;   wsb += (size_t)N_NODES*32*2;
  unsigned short* x1b = (unsigned short*)wsb;   wsb += (size_t)N_NODES*128*2;
  // contiguous zero region: nodeacc + hist
  float* nodeacc = (float*)wsb;                 wsb += (size_t)N_NODES*LAT*4;
  int*   hist    = (int*)wsb;                   wsb += (size_t)N_NODES*4;
  int*   woff    = (int*)wsb;                   wsb += (size_t)N_NODES*4;
  int*   es      = (int*)wsb;                   wsb += (size_t)N_EDGES*4;
  int*   ed      = (int*)wsb;                   wsb += (size_t)N_EDGES*4;
  int*   gstart  = (int*)wsb;                   wsb += 64*4;
  float* pooled  = (float*)wsb;                 wsb += (size_t)N_GRAPHS*LAT*4;

  {
    int zn = N_NODES*LAT + N_NODES;   // nodeacc + hist
    hipLaunchKernelGGL(zero_kernel, dim3((zn+255)/256), dim3(256), 0, stream, nodeacc, zn);
  }
  hipLaunchKernelGGL(hist_kernel, dim3((N_EDGES+255)/256), dim3(256), 0, stream, ei, hist);
  hipLaunchKernelGGL(scan_kernel, dim3(1), dim3(256), 0, stream, hist, woff);
  hipLaunchKernelGGL(sort_kernel, dim3((N_EDGES+255)/256), dim3(256), 0, stream,
                     ei, woff, es, ed);
  hipLaunchKernelGGL(gstart_kernel, dim3((N_NODES+255)/256), dim3(256), 0, stream,
                     batch, gstart);

  // weight / bias prep
  hipLaunchKernelGGL(pack_wfrag, dim3((W2F_ELEMS+255)/256), dim3(256), 0, stream,
                     l0_w2, HID, HID, NCT1, w2f0, (int)W2F_ELEMS);
  hipLaunchKernelGGL(pack_wfrag, dim3((W3F_ELEMS+255)/256), dim3(256), 0, stream,
                     l0_w3, HID, LAT, NCT2, w3f0, (int)W3F_ELEMS);
  hipLaunchKernelGGL(pack_wfrag, dim3((W2F_ELEMS+255)/256), dim3(256), 0, stream,
                     l1_w2, HID, HID, NCT1, w2f1, (int)W2F_ELEMS);
  hipLaunchKernelGGL(pack_wfrag, dim3((W3F_ELEMS+255)/256), dim3(256), 0, stream,
                     l1_w3, HID, LAT, NCT2, w3f1, (int)W3F_ELEMS);
  hipLaunchKernelGGL(pack_w1frag<NODE_F>, dim3((W1F0_ELEMS+255)/256), dim3(256), 0, stream,
                     l0_w1, w1f0, (int)W1F0_ELEMS);
  hipLaunchKernelGGL(pack_w1frag<LAT>, dim3((W1F1_ELEMS+255)/256), dim3(256), 0, stream,
                     l1_w1, w1f1, (int)W1F1_ELEMS);
  hipLaunchKernelGGL(pad_bias4, dim3(2), dim3(256), 0, stream,
                     l0_b1, l0_b2, l1_b1, l1_b2, b1p0, b2p0, b1p1, b2p1);
  hipLaunchKernelGGL(cvt_x0, dim3((N_NODES*32+255)/256), dim3(256), 0, stream, x, xb0);

  const int NGB = (N_NODES + 63)/64;

  // layer 0
  hipLaunchKernelGGL(node_gemm<32>, dim3(NGB), dim3(256), 0, stream, xb0, w1f0, Ub, Vb);
  hipLaunchKernelGGL(edge_mfma, dim3(N_EDGES/EPB), dim3(256), 0, stream,
                     es, ed, Ub, Vb, b1p0, w2f0, b2p0, w3f0, nodeacc);
  hipLaunchKernelGGL(finalize_kernel, dim3((N_NODES*128+255)/256), dim3(256), 0, stream,
                     nodeacc, hist, l0_b3, x1b);

  // layer 1
  hipLaunchKernelGGL(node_gemm<128>, dim3(NGB), dim3(256), 0, stream, x1b, w1f1, Ub, Vb);
  hipLaunchKernelGGL(edge_mfma, dim3(N_EDGES/EPB), dim3(256), 0, stream,
                     es, ed, Ub, Vb, b1p1, w2f1, b2p1, w3f1, nodeacc);
  hipLaunchKernelGGL(finalize_kernel, dim3((N_NODES*128+255)/256), dim3(256), 0, stream,
                     nodeacc, hist, l1_b3, x1b);

  // pooling + head
  hipLaunchKernelGGL(pool_seg, dim3(N_GRAPHS), dim3(512), 0, stream, x1b, gstart, pooled);
  hipLaunchKernelGGL(head_kernel, dim3(1), dim3(128), 0, stream,
                     pooled, u, lin_w1, lin_b1, lin_w2, lin_b2, lin_w3, lin_b3,
                     (float*)d_out);
}